// Round 1
// 4290.885 us; speedup vs baseline: 1.2848x; 1.2848x over previous
//
#include <hip/hip_runtime.h>
#include <cmath>

namespace {

constexpr int L   = 1024;
constexpr int D   = 1024;
constexpr int DFF = 4096;
constexpr int NL  = 3;
constexpr int NH  = 16;
constexpr int DH  = 64;
constexpr long LD = (long)L * D;   // 1048576

typedef __attribute__((ext_vector_type(8))) short bf16x8;  // 8 bf16 (4 VGPRs)
typedef __attribute__((ext_vector_type(4))) float f32x4;   // MFMA C/D

// Split fp32 into hi/lo bf16 (truncation split; x = hi + lo exactly to ~2^-17 rel)
__device__ inline void split1(float f, unsigned short& h, unsigned short& l)
{
    unsigned u = __float_as_uint(f);
    h = (unsigned short)(u >> 16);
    float hf = __uint_as_float(u & 0xffff0000u);
    l = (unsigned short)(__float_as_uint(f - hf) >> 16);
}

// ---------------------------------------------------------------------------
// Split-bf16 MFMA GEMM: C[z] = act(alpha * A[z]@B[z] + bias[z])
//  A: [M x K] row-major (lda, batch stride sA), fp32
//  B: BT=false -> [K x N] (ldb); BT=true -> [N x K] (ldb) i.e. C = A@B^T
//  Internally A,B are split into hi/lo bf16; product = Ah*Bh + Ah*Bl + Al*Bh
//  (fp32-grade accuracy, matrix-pipe speed). M%BM==0, N%BN==0, K%32==0.
// ACT: 0 none, 1 relu, 2 tanh
// 256 threads = 4 waves in 2x2; per-wave tile (BM/2)x(BN/2); 16x16x32 frags.
// ---------------------------------------------------------------------------
template<int BM, int BN, int ACT, bool BT>
__global__ __launch_bounds__(256)
void gemm_mfma(const float* __restrict__ A, int lda, long sA,
               const float* __restrict__ B, int ldb, long sB,
               float* __restrict__ C, int ldc, long sC,
               const float* __restrict__ bias, long sBias,
               int K, float alpha)
{
    constexpr int BK = 32;
    constexpr int PK = 40;              // padded row (bf16): 80B stride, period-8 banks
    constexpr int FM = BM / 32;         // 16x16 frags per wave along M
    constexpr int FN = BN / 32;

    __shared__ unsigned short Ah[BM][PK], Al[BM][PK];
    __shared__ unsigned short Bh[BN][PK], Bl[BN][PK];

    const int tid  = threadIdx.x;
    const int lane = tid & 63;
    const int wave = tid >> 6;
    const int wm   = (wave >> 1) * (BM / 2);
    const int wn   = (wave & 1)  * (BN / 2);
    const int lr   = lane & 15;          // A-row / B-col within fragment
    const int ko   = (lane >> 4) * 8;    // k-octet

    const float* Abase = A + (long)blockIdx.z * sA;
    const float* Bbase = B + (long)blockIdx.z * sB;
    float*       Cbase = C + (long)blockIdx.z * sC;
    const int n0 = blockIdx.x * BN;
    const int m0 = blockIdx.y * BM;

    f32x4 acc[FM][FN];
#pragma unroll
    for (int i = 0; i < FM; ++i)
#pragma unroll
        for (int j = 0; j < FN; ++j) acc[i][j] = f32x4{0.f, 0.f, 0.f, 0.f};

    const int akq = tid & 7;    // float4 chunk within a 32-wide k row
    const int amr = tid >> 3;   // 32 rows per staging pass

    for (int kt = 0; kt < K; kt += BK) {
        // ---- stage A tile: BM x 32 fp32 -> hi/lo bf16, k-contiguous rows
#pragma unroll
        for (int r = 0; r < BM / 32; ++r) {
            int m = r * 32 + amr;
            float4 v = *(const float4*)(Abase + (long)(m0 + m) * lda + kt + akq * 4);
            ushort4 h, l;
            split1(v.x, h.x, l.x); split1(v.y, h.y, l.y);
            split1(v.z, h.z, l.z); split1(v.w, h.w, l.w);
            *(ushort4*)&Ah[m][akq * 4] = h;
            *(ushort4*)&Al[m][akq * 4] = l;
        }
        // ---- stage B tile into Bh/Bl[n][k] (k-contiguous per column n)
        if constexpr (BT) {
#pragma unroll
            for (int r = 0; r < BN / 32; ++r) {
                int n = r * 32 + amr;
                float4 v = *(const float4*)(Bbase + (long)(n0 + n) * ldb + kt + akq * 4);
                ushort4 h, l;
                split1(v.x, h.x, l.x); split1(v.y, h.y, l.y);
                split1(v.z, h.z, l.z); split1(v.w, h.w, l.w);
                *(ushort4*)&Bh[n][akq * 4] = h;
                *(ushort4*)&Bl[n][akq * 4] = l;
            }
        } else {
            constexpr int TPR = BN / 4;      // threads per k-row
            constexpr int RPP = 256 / TPR;   // k-rows per pass
            const int nq = tid % TPR;
            const int kr = tid / TPR;
#pragma unroll
            for (int r = 0; r < BK / RPP; ++r) {
                int k = r * RPP + kr;
                float4 v = *(const float4*)(Bbase + (long)(kt + k) * ldb + n0 + nq * 4);
                ushort4 h, l;
                split1(v.x, h.x, l.x); split1(v.y, h.y, l.y);
                split1(v.z, h.z, l.z); split1(v.w, h.w, l.w);
                Bh[nq * 4 + 0][k] = h.x; Bh[nq * 4 + 1][k] = h.y;
                Bh[nq * 4 + 2][k] = h.z; Bh[nq * 4 + 3][k] = h.w;
                Bl[nq * 4 + 0][k] = l.x; Bl[nq * 4 + 1][k] = l.y;
                Bl[nq * 4 + 2][k] = l.z; Bl[nq * 4 + 3][k] = l.w;
            }
        }
        __syncthreads();

        bf16x8 ah[FM], al[FM], bh[FN], bl[FN];
#pragma unroll
        for (int mi = 0; mi < FM; ++mi) {
            ah[mi] = *(const bf16x8*)&Ah[wm + mi * 16 + lr][ko];
            al[mi] = *(const bf16x8*)&Al[wm + mi * 16 + lr][ko];
        }
#pragma unroll
        for (int ni = 0; ni < FN; ++ni) {
            bh[ni] = *(const bf16x8*)&Bh[wn + ni * 16 + lr][ko];
            bl[ni] = *(const bf16x8*)&Bl[wn + ni * 16 + lr][ko];
        }
#pragma unroll
        for (int mi = 0; mi < FM; ++mi)
#pragma unroll
            for (int ni = 0; ni < FN; ++ni) {
                acc[mi][ni] = __builtin_amdgcn_mfma_f32_16x16x32_bf16(
                    ah[mi], bh[ni], acc[mi][ni], 0, 0, 0);
                acc[mi][ni] = __builtin_amdgcn_mfma_f32_16x16x32_bf16(
                    ah[mi], bl[ni], acc[mi][ni], 0, 0, 0);
                acc[mi][ni] = __builtin_amdgcn_mfma_f32_16x16x32_bf16(
                    al[mi], bh[ni], acc[mi][ni], 0, 0, 0);
            }
        __syncthreads();
    }

    // ---- epilogue: C/D layout col = lane&15, row = (lane>>4)*4 + reg
    float bv[FN];
#pragma unroll
    for (int ni = 0; ni < FN; ++ni)
        bv[ni] = bias ? bias[(long)blockIdx.z * sBias + n0 + wn + ni * 16 + lr] : 0.f;
    const int cr = (lane >> 4) * 4;
#pragma unroll
    for (int mi = 0; mi < FM; ++mi)
#pragma unroll
        for (int ni = 0; ni < FN; ++ni) {
#pragma unroll
            for (int r = 0; r < 4; ++r) {
                float t = acc[mi][ni][r] * alpha + bv[ni];
                if (ACT == 1) t = fmaxf(t, 0.f);
                else if (ACT == 2) t = tanhf(t);
                Cbase[(long)(m0 + wm + mi * 16 + cr + r) * ldc
                      + n0 + wn + ni * 16 + lr] = t;
            }
        }
}

// ---------------------------------------------------------------------------
// x[b] = src + sinusoidal PE, replicated to 3 branches
// ---------------------------------------------------------------------------
__global__ void add_pe_kernel(const float* __restrict__ src, float* __restrict__ x)
{
    long idx = (long)blockIdx.x * 256 + threadIdx.x;   // < LD
    int pos = (int)(idx >> 10);
    int d   = (int)(idx & 1023);
    float expnt = (float)(d & ~1) * (1.0f / (float)D);
    float denom = powf(10000.0f, expnt);
    float ang   = (float)pos / denom;
    float pe    = (d & 1) ? cosf(ang) : sinf(ang);
    float v = src[idx] + pe;
    x[idx]          = v;
    x[LD + idx]     = v;
    x[2 * LD + idx] = v;
}

// ---------------------------------------------------------------------------
// Row-wise masked softmax over S[h][i][:], bias computed on the fly.
// branch: 0=uttm 1=samm 2=othm. In-place. One block (256 thr) per (i,h) row.
// ---------------------------------------------------------------------------
__global__ __launch_bounds__(256)
void softmax_mask_kernel(float* __restrict__ S, const int* __restrict__ utt,
                         const int* __restrict__ spk, const int* __restrict__ winp,
                         int branch)
{
    __shared__ float red[8];
    const int i   = blockIdx.x;
    const int h   = blockIdx.y;
    const int tid = threadIdx.x;
    float* row = S + ((long)h * L + i) * L;
    const int window = winp[0];
    const int utti   = utt[i];
    const int spki   = spk[i];
    const int j0 = tid * 4;

    float4 sv = *(float4*)(row + j0);
    float s[4] = {sv.x, sv.y, sv.z, sv.w};
#pragma unroll
    for (int c = 0; c < 4; ++c) {
        int j = j0 + c;
        int dd = j - i;
        bool win  = (dd <= window) && (-dd <= window);
        bool base = win && (utti > 0) && (utt[j] > 0);
        bool same = (spk[j] == spki);
        bool keep = (branch == 0) ? base
                  : (branch == 1) ? (base && same)
                  : (base && (!same || (j == i)));
        s[c] += keep ? 0.f : -1e9f;
    }
    float mx = fmaxf(fmaxf(s[0], s[1]), fmaxf(s[2], s[3]));
    for (int off = 32; off; off >>= 1) mx = fmaxf(mx, __shfl_xor(mx, off));
    if ((tid & 63) == 0) red[tid >> 6] = mx;
    __syncthreads();
    mx = fmaxf(fmaxf(red[0], red[1]), fmaxf(red[2], red[3]));
    __syncthreads();

    float e[4]; float sum = 0.f;
#pragma unroll
    for (int c = 0; c < 4; ++c) { e[c] = expf(s[c] - mx); sum += e[c]; }
    for (int off = 32; off; off >>= 1) sum += __shfl_xor(sum, off);
    if ((tid & 63) == 0) red[tid >> 6] = sum;
    __syncthreads();
    float inv = 1.f / (red[0] + red[1] + red[2] + red[3]);

    float4 o = {e[0] * inv, e[1] * inv, e[2] * inv, e[3] * inv};
    *(float4*)(row + j0) = o;
}

// ---------------------------------------------------------------------------
// LayerNorm with fused residual: out[row] = LN(x[row]+r[row]) * g + b
// ---------------------------------------------------------------------------
__global__ __launch_bounds__(256)
void ln_kernel(const float* __restrict__ x, const float* __restrict__ r,
               const float* __restrict__ g, const float* __restrict__ b,
               float* __restrict__ out, long paramStride)
{
    __shared__ float red[8];
    const int row = blockIdx.x;
    const int grp = row >> 10;
    const int tid = threadIdx.x;
    const long base = (long)row * D + tid * 4;

    float4 xv = *(const float4*)(x + base);
    float4 rv = *(const float4*)(r + base);
    float4 t  = {xv.x + rv.x, xv.y + rv.y, xv.z + rv.z, xv.w + rv.w};

    float s = t.x + t.y + t.z + t.w;
    for (int off = 32; off; off >>= 1) s += __shfl_xor(s, off);
    if ((tid & 63) == 0) red[tid >> 6] = s;
    __syncthreads();
    float mean = (red[0] + red[1] + red[2] + red[3]) * (1.f / (float)D);
    __syncthreads();

    float4 dv = {t.x - mean, t.y - mean, t.z - mean, t.w - mean};
    float sq = dv.x * dv.x + dv.y * dv.y + dv.z * dv.z + dv.w * dv.w;
    for (int off = 32; off; off >>= 1) sq += __shfl_xor(sq, off);
    if ((tid & 63) == 0) red[tid >> 6] = sq;
    __syncthreads();
    float var  = (red[0] + red[1] + red[2] + red[3]) * (1.f / (float)D);
    float rstd = rsqrtf(var + 1e-5f);

    const float* gp = g + (long)grp * paramStride + tid * 4;
    const float* bp = b + (long)grp * paramStride + tid * 4;
    float4 gv = *(const float4*)gp;
    float4 bv = *(const float4*)bp;
    float4 o = {dv.x * rstd * gv.x + bv.x, dv.y * rstd * gv.y + bv.y,
                dv.z * rstd * gv.z + bv.z, dv.w * rstd * gv.w + bv.w};
    *(float4*)(out + base) = o;
}

// ---------------------------------------------------------------------------
// s[row] = dot(t[row], v)   (rows = 2*L), one block per row
// ---------------------------------------------------------------------------
__global__ __launch_bounds__(256)
void rowdot_kernel(const float* __restrict__ t, const float* __restrict__ v,
                   float* __restrict__ s)
{
    __shared__ float red[8];
    const int row = blockIdx.x;
    const int tid = threadIdx.x;
    float4 tv = *(const float4*)(t + (long)row * D + tid * 4);
    float4 vv = *(const float4*)(v + tid * 4);
    float p = tv.x * vv.x + tv.y * vv.y + tv.z * vv.z + tv.w * vv.w;
    for (int off = 32; off; off >>= 1) p += __shfl_xor(p, off);
    if ((tid & 63) == 0) red[tid >> 6] = p;
    __syncthreads();
    if (tid == 0) s[row] = red[0] + red[1] + red[2] + red[3];
}

// ---------------------------------------------------------------------------
// out[l,d] = softmax_k(sb[k,l])-weighted sum of h[k,l,d], K=2
// ---------------------------------------------------------------------------
__global__ void combine_kernel(const float* __restrict__ sb, const float* __restrict__ h,
                               float* __restrict__ out)
{
    long idx = (long)blockIdx.x * 256 + threadIdx.x;   // < LD
    int l = (int)(idx >> 10);
    float s0 = sb[l], s1 = sb[L + l];
    float m  = fmaxf(s0, s1);
    float e0 = expf(s0 - m), e1 = expf(s1 - m);
    float inv = 1.f / (e0 + e1);
    out[idx] = (e0 * h[idx] + e1 * h[LD + idx]) * inv;
}

// ---------------------------------------------------------------------------
// logits = x @ W[1024x7] + b ; out = log_softmax(logits). One block per row.
// ---------------------------------------------------------------------------
__global__ __launch_bounds__(256)
void cls_kernel(const float* __restrict__ x, const float* __restrict__ W,
                const float* __restrict__ b, float* __restrict__ out)
{
    __shared__ float red[4][7];
    __shared__ float logit[7];
    const int row = blockIdx.x;
    const int tid = threadIdx.x;
    float p[7] = {0, 0, 0, 0, 0, 0, 0};
    for (int d = tid; d < D; d += 256) {
        float xv = x[(long)row * D + d];
#pragma unroll
        for (int c = 0; c < 7; ++c) p[c] = fmaf(xv, W[d * 7 + c], p[c]);
    }
#pragma unroll
    for (int c = 0; c < 7; ++c) {
        float v = p[c];
        for (int off = 32; off; off >>= 1) v += __shfl_xor(v, off);
        if ((tid & 63) == 0) red[tid >> 6][c] = v;
    }
    __syncthreads();
    if (tid < 7)
        logit[tid] = red[0][tid] + red[1][tid] + red[2][tid] + red[3][tid] + b[tid];
    __syncthreads();
    if (tid == 0) {
        float mx = logit[0];
        for (int c = 1; c < 7; ++c) mx = fmaxf(mx, logit[c]);
        float sum = 0.f;
        for (int c = 0; c < 7; ++c) sum += expf(logit[c] - mx);
        float lse = logf(sum) + mx;
        for (int c = 0; c < 7; ++c) out[(long)row * 7 + c] = logit[c] - lse;
    }
}

} // anonymous namespace

extern "C" void kernel_launch(void* const* d_in, const int* in_sizes, int n_in,
                              void* d_out, int out_size, void* d_ws, size_t ws_size,
                              hipStream_t stream)
{
    (void)in_sizes; (void)n_in; (void)out_size; (void)ws_size;

    const float* src  = (const float*)d_in[0];
    const int*   utt  = (const int*)d_in[1];
    const int*   spk  = (const int*)d_in[2];
    const int*   winp = (const int*)d_in[3];
    const float* Wqkv = (const float*)d_in[4];
    const float* bqkv = (const float*)d_in[5];
    const float* Wo   = (const float*)d_in[6];
    const float* bo   = (const float*)d_in[7];
    const float* g1   = (const float*)d_in[8];
    const float* b1   = (const float*)d_in[9];
    const float* Wf1  = (const float*)d_in[10];
    const float* bf1  = (const float*)d_in[11];
    const float* Wf2  = (const float*)d_in[12];
    const float* bf2  = (const float*)d_in[13];
    const float* g2   = (const float*)d_in[14];
    const float* b2   = (const float*)d_in[15];
    const float* f1W  = (const float*)d_in[16];
    const float* f1b  = (const float*)d_in[17];
    const float* f1v  = (const float*)d_in[18];
    const float* f2W  = (const float*)d_in[19];
    const float* f2b  = (const float*)d_in[20];
    const float* f2v  = (const float*)d_in[21];
    const float* clsW = (const float*)d_in[22];
    const float* clsb = (const float*)d_in[23];
    float* out = (float*)d_out;

    // ---- workspace arena (floats). Total = 34*LD + 2048 ≈ 143 MB ----
    float* ws    = (float*)d_ws;
    float* x     = ws;               // 3*LD   [3][L][D]
    float* qkv   = x + 3 * LD;       // 9*LD   [3][L][3D]
    float* attno = qkv + 9 * LD;     // 3*LD
    float* tmp   = attno + 3 * LD;   // 3*LD
    float* R1    = tmp + 3 * LD;     // 16*LD shared region
    float* sbuf  = R1 + 16 * LD;     // 2*L
    float* S    = R1;                // [16][L][L] per-branch scores (attention phase)
    float* ffn  = R1;                // [3][L][DFF] (FFN phase)
    float* tbuf = R1;                // [2][L][D]  (fusion phase)
    float* h2   = R1 + 2 * LD;       // [2][L][D]  (fusion phase)

    add_pe_kernel<<<LD / 256, 256, 0, stream>>>(src, x);

    for (int l = 0; l < NL; ++l) {
        // QKV projection, all 3 branches batched: [L,D]@[D,3D]
        gemm_mfma<128, 128, 0, false>
            <<<dim3(3 * D / 128, L / 128, 3), 256, 0, stream>>>(
            x, D, LD, Wqkv + (long)l * D * 3 * D, 3 * D, (long)NL * D * 3 * D,
            qkv, 3 * D, 3 * LD, bqkv + (long)l * 3 * D, (long)NL * 3 * D, D, 1.f);

        for (int b = 0; b < 3; ++b) {
            const float* qkvb = qkv + (long)b * 3 * LD;
            // scores: S[h] = q@k^T * 0.125  (NT GEMM, K=64, batched over heads)
            gemm_mfma<128, 128, 0, true>
                <<<dim3(L / 128, L / 128, NH), 256, 0, stream>>>(
                qkvb, 3 * D, 64, qkvb + D, 3 * D, 64,
                S, L, (long)L * L, nullptr, 0, DH, 0.125f);
            // masked softmax, bias computed from utt/spk/window on the fly
            softmax_mask_kernel<<<dim3(L, NH), 256, 0, stream>>>(S, utt, spk, winp, b);
            // O[h] = P@V  (M=1024, N=64, K=1024)
            gemm_mfma<128, 64, 0, false>
                <<<dim3(1, L / 128, NH), 256, 0, stream>>>(
                S, L, (long)L * L, qkvb + 2 * D, 3 * D, 64,
                attno + (long)b * LD, D, 64, nullptr, 0, L, 1.f);
        }

        // output projection
        gemm_mfma<128, 128, 0, false>
            <<<dim3(D / 128, L / 128, 3), 256, 0, stream>>>(
            attno, D, LD, Wo + (long)l * D * D, D, (long)NL * D * D,
            tmp, D, LD, bo + (long)l * D, (long)NL * D, D, 1.f);
        ln_kernel<<<3 * L, 256, 0, stream>>>(x, tmp, g1 + (long)l * D, b1 + (long)l * D,
                                             x, (long)NL * D);
        // FFN
        gemm_mfma<128, 128, 1, false>
            <<<dim3(DFF / 128, L / 128, 3), 256, 0, stream>>>(
            x, D, LD, Wf1 + (long)l * D * DFF, DFF, (long)NL * D * DFF,
            ffn, DFF, (long)L * DFF, bf1 + (long)l * DFF, (long)NL * DFF, D, 1.f);
        gemm_mfma<128, 128, 0, false>
            <<<dim3(D / 128, L / 128, 3), 256, 0, stream>>>(
            ffn, DFF, (long)L * DFF, Wf2 + (long)l * DFF * D, D, (long)NL * DFF * D,
            tmp, D, LD, bf2 + (long)l * D, (long)NL * D, DFF, 1.f);
        ln_kernel<<<3 * L, 256, 0, stream>>>(x, tmp, g2 + (long)l * D, b2 + (long)l * D,
                                             x, (long)NL * D);
    }

    // ---- fusion 1: h = [sm, om] = x[1], x[2] ----
    gemm_mfma<128, 128, 2, false>
        <<<dim3(D / 128, L / 128, 2), 256, 0, stream>>>(
        x + LD, D, LD, f1W, D, 0, tbuf, D, LD, f1b, 0, D, 1.f);
    rowdot_kernel<<<2 * L, 256, 0, stream>>>(tbuf, f1v, sbuf);
    combine_kernel<<<LD / 256, 256, 0, stream>>>(sbuf, x + LD, h2 + LD);   // sp -> h2[1]
    hipMemcpyAsync(h2, x, LD * sizeof(float), hipMemcpyDeviceToDevice, stream); // ct -> h2[0]

    // ---- fusion 2: h = [ct, sp] = h2 ----
    gemm_mfma<128, 128, 2, false>
        <<<dim3(D / 128, L / 128, 2), 256, 0, stream>>>(
        h2, D, LD, f2W, D, 0, tbuf, D, LD, f2b, 0, D, 1.f);
    rowdot_kernel<<<2 * L, 256, 0, stream>>>(tbuf, f2v, sbuf);
    combine_kernel<<<LD / 256, 256, 0, stream>>>(sbuf, h2, tmp);           // fused -> tmp

    // ---- classifier + log_softmax ----
    cls_kernel<<<L, 256, 0, stream>>>(tmp, clsW, clsb, out);
}

// Round 2
// 2513.219 us; speedup vs baseline: 2.1935x; 1.7073x over previous
//
#include <hip/hip_runtime.h>
#include <cmath>

namespace {

constexpr int L   = 1024;
constexpr int D   = 1024;
constexpr int DFF = 4096;
constexpr int NL  = 3;
constexpr int NH  = 16;
constexpr int DH  = 64;
constexpr long LD = (long)L * D;   // 1048576

typedef __attribute__((ext_vector_type(8))) short bf16x8;  // 8 bf16 (4 VGPRs)
typedef __attribute__((ext_vector_type(4))) float f32x4;   // MFMA C/D

// Split fp32 into hi/lo bf16 (truncation split; x = hi + lo exactly to ~2^-17 rel)
__device__ inline void split1(float f, unsigned short& h, unsigned short& l)
{
    unsigned u = __float_as_uint(f);
    h = (unsigned short)(u >> 16);
    float hf = __uint_as_float(u & 0xffff0000u);
    l = (unsigned short)(__float_as_uint(f - hf) >> 16);
}

// ---------------------------------------------------------------------------
// Split-bf16 MFMA GEMM: C[z] = act(alpha * A[z]@B[z] + bias[z])
//  A: [M x K] row-major (lda, batch stride sA), fp32
//  B: BT=false -> [K x N] (ldb); BT=true -> [N x K] (ldb) i.e. C = A@B^T
//  Internally A,B are split into hi/lo bf16; product = Ah*Bh + Ah*Bl + Al*Bh
// ACT: 0 none, 1 relu, 2 tanh
// 256 threads = 4 waves in 2x2; per-wave tile (BM/2)x(BN/2); 16x16x32 frags.
// All LDS rows are k-contiguous (80B stride); all LDS writes are ushort4.
// Register prefetch of the next K-tile overlaps HBM latency with MFMA.
// ---------------------------------------------------------------------------
template<int BM, int BN, int ACT, bool BT>
__global__ __launch_bounds__(256)
void gemm_mfma(const float* __restrict__ A, int lda, long sA,
               const float* __restrict__ B, int ldb, long sB,
               float* __restrict__ C, int ldc, long sC,
               const float* __restrict__ bias, long sBias,
               int K, float alpha)
{
    constexpr int BK = 32;
    constexpr int PK = 40;              // padded row (bf16): 80B stride
    constexpr int FM = BM / 32;         // 16x16 frags per wave along M
    constexpr int FN = BN / 32;
    constexpr int NA = BM / 32;         // A float4 loads per thread per tile
    constexpr int KQP = 256 / BN;       // k-quads per pass (col-load path)
    constexpr int NB = BT ? (BN / 32) : (BK / (4 * KQP));   // B regs per tile

    __shared__ unsigned short Ah[BM][PK], Al[BM][PK];
    __shared__ unsigned short Bh[BN][PK], Bl[BN][PK];

    const int tid  = threadIdx.x;
    const int lane = tid & 63;
    const int wave = tid >> 6;
    const int wm   = (wave >> 1) * (BM / 2);
    const int wn   = (wave & 1)  * (BN / 2);
    const int lr   = lane & 15;          // A-row / B-col within fragment
    const int ko   = (lane >> 4) * 8;    // k-octet

    const float* Abase = A + (long)blockIdx.z * sA;
    const float* Bbase = B + (long)blockIdx.z * sB;
    float*       Cbase = C + (long)blockIdx.z * sC;
    const int n0 = blockIdx.x * BN;
    const int m0 = blockIdx.y * BM;

    f32x4 acc[FM][FN];
#pragma unroll
    for (int i = 0; i < FM; ++i)
#pragma unroll
        for (int j = 0; j < FN; ++j) acc[i][j] = f32x4{0.f, 0.f, 0.f, 0.f};

    const int akq = tid & 7;    // float4 chunk within a 32-wide k row
    const int amr = tid >> 3;   // 32 rows per staging pass
    const int nn  = tid % BN;   // col-load path: column
    const int kq0 = tid / BN;   // col-load path: k-quad slot

    auto loadA = [&](int kt, float4* pa) {
#pragma unroll
        for (int r = 0; r < NA; ++r)
            pa[r] = *(const float4*)(Abase + (long)(m0 + r * 32 + amr) * lda + kt + akq * 4);
    };
    auto loadB = [&](int kt, float4* pb) {
        if constexpr (BT) {
#pragma unroll
            for (int r = 0; r < NB; ++r)
                pb[r] = *(const float4*)(Bbase + (long)(n0 + r * 32 + amr) * ldb + kt + akq * 4);
        } else {
#pragma unroll
            for (int r = 0; r < NB; ++r) {
                const int k = (r * KQP + kq0) * 4;
                pb[r].x = Bbase[(long)(kt + k + 0) * ldb + n0 + nn];
                pb[r].y = Bbase[(long)(kt + k + 1) * ldb + n0 + nn];
                pb[r].z = Bbase[(long)(kt + k + 2) * ldb + n0 + nn];
                pb[r].w = Bbase[(long)(kt + k + 3) * ldb + n0 + nn];
            }
        }
    };
    auto storeA = [&](const float4* pa) {
#pragma unroll
        for (int r = 0; r < NA; ++r) {
            ushort4 h, l;
            split1(pa[r].x, h.x, l.x); split1(pa[r].y, h.y, l.y);
            split1(pa[r].z, h.z, l.z); split1(pa[r].w, h.w, l.w);
            *(ushort4*)&Ah[r * 32 + amr][akq * 4] = h;
            *(ushort4*)&Al[r * 32 + amr][akq * 4] = l;
        }
    };
    auto storeB = [&](const float4* pb) {
        if constexpr (BT) {
#pragma unroll
            for (int r = 0; r < NB; ++r) {
                ushort4 h, l;
                split1(pb[r].x, h.x, l.x); split1(pb[r].y, h.y, l.y);
                split1(pb[r].z, h.z, l.z); split1(pb[r].w, h.w, l.w);
                *(ushort4*)&Bh[r * 32 + amr][akq * 4] = h;
                *(ushort4*)&Bl[r * 32 + amr][akq * 4] = l;
            }
        } else {
#pragma unroll
            for (int r = 0; r < NB; ++r) {
                const int k = (r * KQP + kq0) * 4;
                ushort4 h, l;
                split1(pb[r].x, h.x, l.x); split1(pb[r].y, h.y, l.y);
                split1(pb[r].z, h.z, l.z); split1(pb[r].w, h.w, l.w);
                *(ushort4*)&Bh[nn][k] = h;
                *(ushort4*)&Bl[nn][k] = l;
            }
        }
    };

    float4 pa[NA], pb[NB];
    loadA(0, pa); loadB(0, pb);

    for (int kt = 0; kt < K; kt += BK) {
        storeA(pa);
        storeB(pb);
        __syncthreads();

        float4 na[NA], nb[NB];
        if (kt + BK < K) { loadA(kt + BK, na); loadB(kt + BK, nb); }

        bf16x8 ah[FM], al[FM], bh[FN], bl[FN];
#pragma unroll
        for (int mi = 0; mi < FM; ++mi) {
            ah[mi] = *(const bf16x8*)&Ah[wm + mi * 16 + lr][ko];
            al[mi] = *(const bf16x8*)&Al[wm + mi * 16 + lr][ko];
        }
#pragma unroll
        for (int ni = 0; ni < FN; ++ni) {
            bh[ni] = *(const bf16x8*)&Bh[wn + ni * 16 + lr][ko];
            bl[ni] = *(const bf16x8*)&Bl[wn + ni * 16 + lr][ko];
        }
#pragma unroll
        for (int mi = 0; mi < FM; ++mi)
#pragma unroll
            for (int ni = 0; ni < FN; ++ni) {
                acc[mi][ni] = __builtin_amdgcn_mfma_f32_16x16x32_bf16(
                    ah[mi], bh[ni], acc[mi][ni], 0, 0, 0);
                acc[mi][ni] = __builtin_amdgcn_mfma_f32_16x16x32_bf16(
                    ah[mi], bl[ni], acc[mi][ni], 0, 0, 0);
                acc[mi][ni] = __builtin_amdgcn_mfma_f32_16x16x32_bf16(
                    al[mi], bh[ni], acc[mi][ni], 0, 0, 0);
            }
        __syncthreads();

#pragma unroll
        for (int r = 0; r < NA; ++r) pa[r] = na[r];
#pragma unroll
        for (int r = 0; r < NB; ++r) pb[r] = nb[r];
    }

    // ---- epilogue: C/D layout col = lane&15, row = (lane>>4)*4 + reg
    float bv[FN];
#pragma unroll
    for (int ni = 0; ni < FN; ++ni)
        bv[ni] = bias ? bias[(long)blockIdx.z * sBias + n0 + wn + ni * 16 + lr] : 0.f;
    const int cr = (lane >> 4) * 4;
#pragma unroll
    for (int mi = 0; mi < FM; ++mi)
#pragma unroll
        for (int ni = 0; ni < FN; ++ni) {
#pragma unroll
            for (int r = 0; r < 4; ++r) {
                float t = acc[mi][ni][r] * alpha + bv[ni];
                if (ACT == 1) t = fmaxf(t, 0.f);
                else if (ACT == 2) t = tanhf(t);
                Cbase[(long)(m0 + wm + mi * 16 + cr + r) * ldc
                      + n0 + wn + ni * 16 + lr] = t;
            }
        }
}

// ---------------------------------------------------------------------------
// x[b] = src + sinusoidal PE, replicated to 3 branches
// ---------------------------------------------------------------------------
__global__ void add_pe_kernel(const float* __restrict__ src, float* __restrict__ x)
{
    long idx = (long)blockIdx.x * 256 + threadIdx.x;   // < LD
    int pos = (int)(idx >> 10);
    int d   = (int)(idx & 1023);
    float expnt = (float)(d & ~1) * (1.0f / (float)D);
    float denom = powf(10000.0f, expnt);
    float ang   = (float)pos / denom;
    float pe    = (d & 1) ? cosf(ang) : sinf(ang);
    float v = src[idx] + pe;
    x[idx]          = v;
    x[LD + idx]     = v;
    x[2 * LD + idx] = v;
}

// ---------------------------------------------------------------------------
// Row-wise masked softmax over S[h][i][:], bias computed on the fly.
// branch: 0=uttm 1=samm 2=othm. In-place. One block (256 thr) per (i,h) row.
// ---------------------------------------------------------------------------
__global__ __launch_bounds__(256)
void softmax_mask_kernel(float* __restrict__ S, const int* __restrict__ utt,
                         const int* __restrict__ spk, const int* __restrict__ winp,
                         int branch)
{
    __shared__ float red[8];
    const int i   = blockIdx.x;
    const int h   = blockIdx.y;
    const int tid = threadIdx.x;
    float* row = S + ((long)h * L + i) * L;
    const int window = winp[0];
    const int utti   = utt[i];
    const int spki   = spk[i];
    const int j0 = tid * 4;

    float4 sv = *(float4*)(row + j0);
    float s[4] = {sv.x, sv.y, sv.z, sv.w};
#pragma unroll
    for (int c = 0; c < 4; ++c) {
        int j = j0 + c;
        int dd = j - i;
        bool win  = (dd <= window) && (-dd <= window);
        bool base = win && (utti > 0) && (utt[j] > 0);
        bool same = (spk[j] == spki);
        bool keep = (branch == 0) ? base
                  : (branch == 1) ? (base && same)
                  : (base && (!same || (j == i)));
        s[c] += keep ? 0.f : -1e9f;
    }
    float mx = fmaxf(fmaxf(s[0], s[1]), fmaxf(s[2], s[3]));
    for (int off = 32; off; off >>= 1) mx = fmaxf(mx, __shfl_xor(mx, off));
    if ((tid & 63) == 0) red[tid >> 6] = mx;
    __syncthreads();
    mx = fmaxf(fmaxf(red[0], red[1]), fmaxf(red[2], red[3]));
    __syncthreads();

    float e[4]; float sum = 0.f;
#pragma unroll
    for (int c = 0; c < 4; ++c) { e[c] = expf(s[c] - mx); sum += e[c]; }
    for (int off = 32; off; off >>= 1) sum += __shfl_xor(sum, off);
    if ((tid & 63) == 0) red[tid >> 6] = sum;
    __syncthreads();
    float inv = 1.f / (red[0] + red[1] + red[2] + red[3]);

    float4 o = {e[0] * inv, e[1] * inv, e[2] * inv, e[3] * inv};
    *(float4*)(row + j0) = o;
}

// ---------------------------------------------------------------------------
// LayerNorm with fused residual: out[row] = LN(x[row]+r[row]) * g + b
// ---------------------------------------------------------------------------
__global__ __launch_bounds__(256)
void ln_kernel(const float* __restrict__ x, const float* __restrict__ r,
               const float* __restrict__ g, const float* __restrict__ b,
               float* __restrict__ out, long paramStride)
{
    __shared__ float red[8];
    const int row = blockIdx.x;
    const int grp = row >> 10;
    const int tid = threadIdx.x;
    const long base = (long)row * D + tid * 4;

    float4 xv = *(const float4*)(x + base);
    float4 rv = *(const float4*)(r + base);
    float4 t  = {xv.x + rv.x, xv.y + rv.y, xv.z + rv.z, xv.w + rv.w};

    float s = t.x + t.y + t.z + t.w;
    for (int off = 32; off; off >>= 1) s += __shfl_xor(s, off);
    if ((tid & 63) == 0) red[tid >> 6] = s;
    __syncthreads();
    float mean = (red[0] + red[1] + red[2] + red[3]) * (1.f / (float)D);
    __syncthreads();

    float4 dv = {t.x - mean, t.y - mean, t.z - mean, t.w - mean};
    float sq = dv.x * dv.x + dv.y * dv.y + dv.z * dv.z + dv.w * dv.w;
    for (int off = 32; off; off >>= 1) sq += __shfl_xor(sq, off);
    if ((tid & 63) == 0) red[tid >> 6] = sq;
    __syncthreads();
    float var  = (red[0] + red[1] + red[2] + red[3]) * (1.f / (float)D);
    float rstd = rsqrtf(var + 1e-5f);

    const float* gp = g + (long)grp * paramStride + tid * 4;
    const float* bp = b + (long)grp * paramStride + tid * 4;
    float4 gv = *(const float4*)gp;
    float4 bv = *(const float4*)bp;
    float4 o = {dv.x * rstd * gv.x + bv.x, dv.y * rstd * gv.y + bv.y,
                dv.z * rstd * gv.z + bv.z, dv.w * rstd * gv.w + bv.w};
    *(float4*)(out + base) = o;
}

// ---------------------------------------------------------------------------
// s[row] = dot(t[row], v)   (rows = 2*L), one block per row
// ---------------------------------------------------------------------------
__global__ __launch_bounds__(256)
void rowdot_kernel(const float* __restrict__ t, const float* __restrict__ v,
                   float* __restrict__ s)
{
    __shared__ float red[8];
    const int row = blockIdx.x;
    const int tid = threadIdx.x;
    float4 tv = *(const float4*)(t + (long)row * D + tid * 4);
    float4 vv = *(const float4*)(v + tid * 4);
    float p = tv.x * vv.x + tv.y * vv.y + tv.z * vv.z + tv.w * vv.w;
    for (int off = 32; off; off >>= 1) p += __shfl_xor(p, off);
    if ((tid & 63) == 0) red[tid >> 6] = p;
    __syncthreads();
    if (tid == 0) s[row] = red[0] + red[1] + red[2] + red[3];
}

// ---------------------------------------------------------------------------
// out[l,d] = softmax_k(sb[k,l])-weighted sum of h[k,l,d], K=2
// ---------------------------------------------------------------------------
__global__ void combine_kernel(const float* __restrict__ sb, const float* __restrict__ h,
                               float* __restrict__ out)
{
    long idx = (long)blockIdx.x * 256 + threadIdx.x;   // < LD
    int l = (int)(idx >> 10);
    float s0 = sb[l], s1 = sb[L + l];
    float m  = fmaxf(s0, s1);
    float e0 = expf(s0 - m), e1 = expf(s1 - m);
    float inv = 1.f / (e0 + e1);
    out[idx] = (e0 * h[idx] + e1 * h[LD + idx]) * inv;
}

// ---------------------------------------------------------------------------
// logits = x @ W[1024x7] + b ; out = log_softmax(logits). One block per row.
// ---------------------------------------------------------------------------
__global__ __launch_bounds__(256)
void cls_kernel(const float* __restrict__ x, const float* __restrict__ W,
                const float* __restrict__ b, float* __restrict__ out)
{
    __shared__ float red[4][7];
    __shared__ float logit[7];
    const int row = blockIdx.x;
    const int tid = threadIdx.x;
    float p[7] = {0, 0, 0, 0, 0, 0, 0};
    for (int d = tid; d < D; d += 256) {
        float xv = x[(long)row * D + d];
#pragma unroll
        for (int c = 0; c < 7; ++c) p[c] = fmaf(xv, W[d * 7 + c], p[c]);
    }
#pragma unroll
    for (int c = 0; c < 7; ++c) {
        float v = p[c];
        for (int off = 32; off; off >>= 1) v += __shfl_xor(v, off);
        if ((tid & 63) == 0) red[tid >> 6][c] = v;
    }
    __syncthreads();
    if (tid < 7)
        logit[tid] = red[0][tid] + red[1][tid] + red[2][tid] + red[3][tid] + b[tid];
    __syncthreads();
    if (tid == 0) {
        float mx = logit[0];
        for (int c = 1; c < 7; ++c) mx = fmaxf(mx, logit[c]);
        float sum = 0.f;
        for (int c = 0; c < 7; ++c) sum += expf(logit[c] - mx);
        float lse = logf(sum) + mx;
        for (int c = 0; c < 7; ++c) out[(long)row * 7 + c] = logit[c] - lse;
    }
}

} // anonymous namespace

extern "C" void kernel_launch(void* const* d_in, const int* in_sizes, int n_in,
                              void* d_out, int out_size, void* d_ws, size_t ws_size,
                              hipStream_t stream)
{
    (void)in_sizes; (void)n_in; (void)out_size; (void)ws_size;

    const float* src  = (const float*)d_in[0];
    const int*   utt  = (const int*)d_in[1];
    const int*   spk  = (const int*)d_in[2];
    const int*   winp = (const int*)d_in[3];
    const float* Wqkv = (const float*)d_in[4];
    const float* bqkv = (const float*)d_in[5];
    const float* Wo   = (const float*)d_in[6];
    const float* bo   = (const float*)d_in[7];
    const float* g1   = (const float*)d_in[8];
    const float* b1   = (const float*)d_in[9];
    const float* Wf1  = (const float*)d_in[10];
    const float* bf1  = (const float*)d_in[11];
    const float* Wf2  = (const float*)d_in[12];
    const float* bf2  = (const float*)d_in[13];
    const float* g2   = (const float*)d_in[14];
    const float* b2   = (const float*)d_in[15];
    const float* f1W  = (const float*)d_in[16];
    const float* f1b  = (const float*)d_in[17];
    const float* f1v  = (const float*)d_in[18];
    const float* f2W  = (const float*)d_in[19];
    const float* f2b  = (const float*)d_in[20];
    const float* f2v  = (const float*)d_in[21];
    const float* clsW = (const float*)d_in[22];
    const float* clsb = (const float*)d_in[23];
    float* out = (float*)d_out;

    // ---- workspace arena (floats). Total = 34*LD + 2048 ≈ 143 MB ----
    float* ws    = (float*)d_ws;
    float* x     = ws;               // 3*LD   [3][L][D]
    float* qkv   = x + 3 * LD;       // 9*LD   [3][L][3D]
    float* attno = qkv + 9 * LD;     // 3*LD
    float* tmp   = attno + 3 * LD;   // 3*LD
    float* R1    = tmp + 3 * LD;     // 16*LD shared region
    float* sbuf  = R1 + 16 * LD;     // 2*L
    float* S    = R1;                // [16][L][L] per-branch scores (attention phase)
    float* ffn  = R1;                // [3][L][DFF] (FFN phase)
    float* tbuf = R1;                // [2][L][D]  (fusion phase)
    float* h2   = R1 + 2 * LD;       // [2][L][D]  (fusion phase)

    add_pe_kernel<<<LD / 256, 256, 0, stream>>>(src, x);

    for (int l = 0; l < NL; ++l) {
        // QKV projection, all 3 branches batched: [L,D]@[D,3D]
        gemm_mfma<128, 128, 0, false>
            <<<dim3(3 * D / 128, L / 128, 3), 256, 0, stream>>>(
            x, D, LD, Wqkv + (long)l * D * 3 * D, 3 * D, (long)NL * D * 3 * D,
            qkv, 3 * D, 3 * LD, bqkv + (long)l * 3 * D, (long)NL * 3 * D, D, 1.f);

        for (int b = 0; b < 3; ++b) {
            const float* qkvb = qkv + (long)b * 3 * LD;
            // scores: S[h] = q@k^T * 0.125  (NT GEMM, K=64, batched over heads)
            gemm_mfma<128, 128, 0, true>
                <<<dim3(L / 128, L / 128, NH), 256, 0, stream>>>(
                qkvb, 3 * D, 64, qkvb + D, 3 * D, 64,
                S, L, (long)L * L, nullptr, 0, DH, 0.125f);
            // masked softmax, bias computed from utt/spk/window on the fly
            softmax_mask_kernel<<<dim3(L, NH), 256, 0, stream>>>(S, utt, spk, winp, b);
            // O[h] = P@V  (M=1024, N=64, K=1024)
            gemm_mfma<128, 64, 0, false>
                <<<dim3(1, L / 128, NH), 256, 0, stream>>>(
                S, L, (long)L * L, qkvb + 2 * D, 3 * D, 64,
                attno + (long)b * LD, D, 64, nullptr, 0, L, 1.f);
        }

        // output projection
        gemm_mfma<128, 128, 0, false>
            <<<dim3(D / 128, L / 128, 3), 256, 0, stream>>>(
            attno, D, LD, Wo + (long)l * D * D, D, (long)NL * D * D,
            tmp, D, LD, bo + (long)l * D, (long)NL * D, D, 1.f);
        ln_kernel<<<3 * L, 256, 0, stream>>>(x, tmp, g1 + (long)l * D, b1 + (long)l * D,
                                             x, (long)NL * D);
        // FFN
        gemm_mfma<128, 128, 1, false>
            <<<dim3(DFF / 128, L / 128, 3), 256, 0, stream>>>(
            x, D, LD, Wf1 + (long)l * D * DFF, DFF, (long)NL * D * DFF,
            ffn, DFF, (long)L * DFF, bf1 + (long)l * DFF, (long)NL * DFF, D, 1.f);
        gemm_mfma<128, 128, 0, false>
            <<<dim3(D / 128, L / 128, 3), 256, 0, stream>>>(
            ffn, DFF, (long)L * DFF, Wf2 + (long)l * DFF * D, D, (long)NL * DFF * D,
            tmp, D, LD, bf2 + (long)l * D, (long)NL * D, DFF, 1.f);
        ln_kernel<<<3 * L, 256, 0, stream>>>(x, tmp, g2 + (long)l * D, b2 + (long)l * D,
                                             x, (long)NL * D);
    }

    // ---- fusion 1: h = [sm, om] = x[1], x[2] ----
    gemm_mfma<128, 128, 2, false>
        <<<dim3(D / 128, L / 128, 2), 256, 0, stream>>>(
        x + LD, D, LD, f1W, D, 0, tbuf, D, LD, f1b, 0, D, 1.f);
    rowdot_kernel<<<2 * L, 256, 0, stream>>>(tbuf, f1v, sbuf);
    combine_kernel<<<LD / 256, 256, 0, stream>>>(sbuf, x + LD, h2 + LD);   // sp -> h2[1]
    hipMemcpyAsync(h2, x, LD * sizeof(float), hipMemcpyDeviceToDevice, stream); // ct -> h2[0]

    // ---- fusion 2: h = [ct, sp] = h2 ----
    gemm_mfma<128, 128, 2, false>
        <<<dim3(D / 128, L / 128, 2), 256, 0, stream>>>(
        h2, D, LD, f2W, D, 0, tbuf, D, LD, f2b, 0, D, 1.f);
    rowdot_kernel<<<2 * L, 256, 0, stream>>>(tbuf, f2v, sbuf);
    combine_kernel<<<LD / 256, 256, 0, stream>>>(sbuf, h2, tmp);           // fused -> tmp

    // ---- classifier + log_softmax ----
    cls_kernel<<<L, 256, 0, stream>>>(tmp, clsW, clsb, out);
}